// Round 10
// baseline (188.607 us; speedup 1.0000x reference)
//
#include <hip/hip_runtime.h>
#include <math.h>

typedef __bf16 bf16x8 __attribute__((ext_vector_type(8)));
typedef float f32x4 __attribute__((ext_vector_type(4)));

#define NB 4
#define NT 48
#define NV 32
#define ND 512
#define NH 8
#define NN 1536   // T*V
#define NBN 6144  // B*N
#define L2E 1.44269504f

#define GLOAD_LDS(g, l) \
    __builtin_amdgcn_global_load_lds( \
        (const __attribute__((address_space(1))) void*)(g), \
        (__attribute__((address_space(3))) void*)(l), 16, 0, 0)

// ---------------------------------------------------------------------------
// prep: fused conv_h (blocks 0..1535) + weight transpose (1536..1791) +
// kx obs/zero segments (1792..2175).  log2e folded into Wq/bq scale.
// ---------------------------------------------------------------------------
__global__ __launch_bounds__(256) void prep(
    const float* __restrict__ h, const float* __restrict__ obs,
    const float* __restrict__ Wq, const float* __restrict__ Wk,
    const float* __restrict__ Wv, const float* __restrict__ Wo,
    const float* __restrict__ bq, const float* __restrict__ bk,
    const float* __restrict__ bv,
    const float* __restrict__ Wok, const float* __restrict__ bok,
    __bf16* __restrict__ h_bf, __bf16* __restrict__ WcatT,
    __bf16* __restrict__ WoT, float* __restrict__ biascat,
    __bf16* __restrict__ kx)
{
    __shared__ float ts[64][68];
    const int tid = threadIdx.x;
    const int bx = blockIdx.x;
    if (bx < 1536) {
        int t = bx * 256 + tid;
        const float4* src = (const float4*)h + (size_t)t * 2;
        float4 a = src[0], b = src[1];
        __bf16 r[8] = {(__bf16)a.x, (__bf16)a.y, (__bf16)a.z, (__bf16)a.w,
                       (__bf16)b.x, (__bf16)b.y, (__bf16)b.z, (__bf16)b.w};
        *(uint4*)(h_bf + (size_t)t * 8) = *(uint4*)r;
    } else if (bx < 1792) {
        int bw = bx - 1536;
        const int p = bw >> 6, tile = bw & 63;
        const int k0 = (tile >> 3) * 64, c0 = (tile & 7) * 64;
        const float* W = (p == 0) ? Wq : (p == 1) ? Wk : (p == 2) ? Wv : Wo;
        const float scale = (p == 0) ? 0.125f * L2E : 1.0f;
        #pragma unroll
        for (int i = 0; i < 4; i++) {
            int r = (tid >> 4) + i * 16;
            float4 v = *(const float4*)(W + (size_t)(k0 + r) * 512 + c0 + (tid & 15) * 4);
            *(float4*)&ts[r][(tid & 15) * 4] = v;
        }
        __syncthreads();
        __bf16 tmp[16];
        #pragma unroll
        for (int j = 0; j < 16; j++)
            tmp[j] = (__bf16)(ts[(tid & 3) * 16 + j][tid >> 2] * scale);
        int crow = c0 + (tid >> 2);
        __bf16* dst = (p < 3)
            ? WcatT + ((size_t)(p * 512 + crow)) * 512 + k0 + (tid & 3) * 16
            : WoT   + ((size_t)crow) * 512 + k0 + (tid & 3) * 16;
        *(uint4*)dst = *(uint4*)tmp;
        *(uint4*)(dst + 8) = *(uint4*)(tmp + 8);
        if (p < 3 && k0 == 0 && tid < 64) {
            const float* bb = (p == 0) ? bq : (p == 1) ? bk : bv;
            biascat[p * 512 + c0 + tid] = bb[c0 + tid] * scale;
        }
    } else {
        int t = (bx - 1792) * 256 + tid;               // 0..98303
        int row = t >> 1, half = t & 1;                // row = bh*1536 + n
        __bf16* dst = kx + (size_t)row * 96 + 64 + half * 16;
        if (half == 0) {
            int bh = row / NN, n = row - bh * NN;
            int b = bh >> 3, hh = bh & 7;
            size_t bn = (size_t)b * NN + n;
            float o0 = obs[bn * 2], o1 = obs[bn * 2 + 1];
            int f = hh * 16;
            __bf16 tmp[16];
            #pragma unroll
            for (int j = 0; j < 16; j++)
                tmp[j] = (__bf16)(o0 * Wok[f + j] + o1 * Wok[128 + f + j] + bok[f + j]);
            *(uint4*)dst       = *(uint4*)tmp;
            *(uint4*)(dst + 8) = *(uint4*)(tmp + 8);
        } else {
            uint4 z = {0, 0, 0, 0};
            *(uint4*)dst       = z;
            *(uint4*)(dst + 8) = z;
        }
    }
}

// ---------------------------------------------------------------------------
// kvprep: V transpose only. vt[(b*8+h)*64 + d][n] = varr[b*NN+n][h*64+d].
// grid (24, 32).
// ---------------------------------------------------------------------------
__global__ __launch_bounds__(256) void kvprep(const __bf16* __restrict__ varr,
                                              __bf16* __restrict__ vt)
{
    __shared__ __bf16 ts[64][72];
    const int tid = threadIdx.x;
    const int nt = blockIdx.x, bh = blockIdx.y;
    const int b = bh >> 3, h = bh & 7;
    const int n0 = nt * 64;
    const __bf16* src = varr + (size_t)(b * NN + n0 + (tid >> 2)) * 512
                             + h * 64 + (tid & 3) * 16;
    *(uint4*)&ts[tid >> 2][(tid & 3) * 16]     = *(const uint4*)src;
    *(uint4*)&ts[tid >> 2][(tid & 3) * 16 + 8] = *(const uint4*)(src + 8);
    __syncthreads();
    __bf16 tmp[16];
    #pragma unroll
    for (int j = 0; j < 16; j++)
        tmp[j] = ts[(tid & 3) * 16 + j][tid >> 2];
    __bf16* dst = vt + ((size_t)bh * 64 + (tid >> 2)) * 1536 + n0 + (tid & 3) * 16;
    *(uint4*)dst       = *(uint4*)tmp;
    *(uint4*)(dst + 8) = *(uint4*)(tmp + 8);
}

// ---------------------------------------------------------------------------
// bf16 MFMA GEMM (global_load_lds staging + XOR-swizzled LDS).
// LDS-staged epilogue: acc -> Cs tile -> coalesced b128 global stores.
// BF16OUT (QKV): routes 64-col blocks to qarr / kx(head-scattered) / varr.
// else: fp32 out [M][512].
// ---------------------------------------------------------------------------
template<int TM, bool BF16OUT>
__global__ __launch_bounds__(256) void gemm_mfma(
    const __bf16* __restrict__ A, const __bf16* __restrict__ Bt,
    const float* __restrict__ bias, float* __restrict__ Cf,
    __bf16* __restrict__ qarr, __bf16* __restrict__ kx,
    __bf16* __restrict__ varr)
{
    constexpr int MT = TM / 32;
    __shared__ __align__(16) char smem[33792];
    __bf16 (*As)[32] = (__bf16(*)[32])smem;
    __bf16 (*Bs)[32] = (__bf16(*)[32])(smem + TM * 64);
    const int tid = threadIdx.x;
    const int w = tid >> 6, lane = tid & 63;
    const int quad = lane >> 4, l16 = lane & 15;
    const int wm = w >> 1, wn = w & 1;
    const int n0 = blockIdx.x * 128, m0 = blockIdx.y * TM;

    const int sm = tid >> 2;
    const int sk = ((tid & 3) ^ ((sm >> 1) & 3)) * 8;
    const __bf16* aptr = A  + (size_t)(m0 + sm) * 512 + sk;
    const __bf16* bptr = Bt + (size_t)(n0 + sm) * 512 + sk;
    __bf16* lA = (__bf16*)As + tid * 8;
    __bf16* lB = (__bf16*)Bs + tid * 8;

    f32x4 zero4 = {0.f, 0.f, 0.f, 0.f};
    f32x4 acc[MT][4];
    #pragma unroll
    for (int i = 0; i < MT; i++)
        #pragma unroll
        for (int j = 0; j < 4; j++) acc[i][j] = zero4;

    for (int kt = 0; kt < 512; kt += 32) {
        __syncthreads();
        GLOAD_LDS(aptr + kt, lA);
        if (TM == 128) GLOAD_LDS(aptr + 64 * 512 + kt, lA + 2048);
        GLOAD_LDS(bptr + kt, lB);
        GLOAD_LDS(bptr + 64 * 512 + kt, lB + 2048);
        __syncthreads();
        bf16x8 af[MT], bfr[4];
        #pragma unroll
        for (int mt = 0; mt < MT; mt++) {
            int rr = wm * (TM / 2) + mt * 16 + l16;
            af[mt] = *(const bf16x8*)&As[rr][(quad ^ ((rr >> 1) & 3)) * 8];
        }
        #pragma unroll
        for (int nt = 0; nt < 4; nt++) {
            int rr = wn * 64 + nt * 16 + l16;
            bfr[nt] = *(const bf16x8*)&Bs[rr][(quad ^ ((rr >> 1) & 3)) * 8];
        }
        #pragma unroll
        for (int mt = 0; mt < MT; mt++)
            #pragma unroll
            for (int nt = 0; nt < 4; nt++)
                acc[mt][nt] = __builtin_amdgcn_mfma_f32_16x16x32_bf16(
                    af[mt], bfr[nt], acc[mt][nt], 0, 0, 0);
    }

    __syncthreads();   // frag reads done; smem becomes Cs
    if (BF16OUT) {
        __bf16* Cs = (__bf16*)smem;               // [TM][132]
        #pragma unroll
        for (int mt = 0; mt < MT; mt++)
            #pragma unroll
            for (int nt = 0; nt < 4; nt++) {
                int c = n0 + wn * 64 + nt * 16 + l16;
                float bia = bias[c];
                int cl = wn * 64 + nt * 16 + l16;
                #pragma unroll
                for (int r = 0; r < 4; r++) {
                    int rl = wm * (TM / 2) + mt * 16 + quad * 4 + r;
                    Cs[rl * 132 + cl] = (__bf16)(acc[mt][nt][r] + bia);
                }
            }
        __syncthreads();
        int rl = tid >> 1, hb = tid & 1;
        int grow = m0 + rl;
        int col0 = n0 + hb * 64;
        int p = col0 >> 9, f0 = col0 & 511, hh = f0 >> 6;
        int bidx = grow / NN, n = grow - bidx * NN;
        __bf16* dst = (p == 0) ? qarr + (size_t)grow * 512 + f0
                    : (p == 1) ? kx + ((size_t)(bidx * 8 + hh) * NN + n) * 96
                               : varr + (size_t)grow * 512 + f0;
        #pragma unroll
        for (int j = 0; j < 8; j++) {
            uint2 lo = *(uint2*)&Cs[rl * 132 + hb * 64 + j * 8];
            uint2 hi = *(uint2*)&Cs[rl * 132 + hb * 64 + j * 8 + 4];
            uint4 v = {lo.x, lo.y, hi.x, hi.y};
            *(uint4*)(dst + j * 8) = v;
        }
    } else {
        float* Csf = (float*)smem;                // [64][132]
        #pragma unroll
        for (int mt = 0; mt < MT; mt++)
            #pragma unroll
            for (int nt = 0; nt < 4; nt++) {
                int c = n0 + wn * 64 + nt * 16 + l16;
                float bia = bias[c];
                int cl = wn * 64 + nt * 16 + l16;
                #pragma unroll
                for (int r = 0; r < 4; r++) {
                    int rl = wm * (TM / 2) + mt * 16 + quad * 4 + r;
                    Csf[rl * 132 + cl] = acc[mt][nt][r] + bia;
                }
            }
        __syncthreads();
        int rl = tid >> 2, q4 = tid & 3;
        float* dst = Cf + (size_t)(m0 + rl) * 512 + n0 + q4 * 32;
        #pragma unroll
        for (int j = 0; j < 8; j++) {
            uint4 v = *(uint4*)&Csf[rl * 132 + q4 * 32 + j * 4];
            *(uint4*)(dst + j * 4) = v;
        }
    }
}

// ---------------------------------------------------------------------------
// Flash attention, TRANSPOSED orientation: S^T = K.Q^T, O^T = V^T.P^T.
// Lane holds m-consecutive P values -> packed b64 P-stores, b128 P-reads,
// 2-shuffle l-reduction, packed b64 epilogue. K/V GLOAD staging identical
// to the R9-proven kernel. LDS ~32.4 KB, grid 24x32.
// ---------------------------------------------------------------------------
__global__ __launch_bounds__(256) void attn_mfma(
    const __bf16* __restrict__ qarr, const __bf16* __restrict__ kx,
    const __bf16* __restrict__ vt, const float* __restrict__ obs,
    const float* __restrict__ Woq, const float* __restrict__ boq,
    const float* __restrict__ varb, const float* __restrict__ rtb,
    __bf16* __restrict__ aout)
{
    __shared__ __align__(16) __bf16 Ks[64][128];  // [m][128]: 8 content,4 obs,4 junk
    __shared__ __align__(16) __bf16 Vs[64][64];   // [d][m] swizzled (as before)
    __shared__ __align__(16) __bf16 Ps[64][64];   // [n][m] chunk-XOR swizzled
    __shared__ float rts[96];

    const int tid = threadIdx.x;
    const int w = tid >> 6, lane = tid & 63;
    const int quad = lane >> 4, l16 = lane & 15;
    const int qt = blockIdx.x, bh = blockIdx.y;
    const int b = bh >> 3, h = bh & 7;
    const int n0 = qt * 64;

    if (tid < 95) rts[tid] = rtb[h * 95 + tid] * L2E;

    // Q fragments (B-operand): lane l16 holds row n = w*16+l16
    const int nl = w * 16 + l16;
    const size_t qrow = (size_t)(b * NN + n0 + nl);
    bf16x8 bq_[3];
    bq_[0] = *(const bf16x8*)(qarr + qrow * 512 + h * 64 + quad * 8);
    bq_[1] = *(const bf16x8*)(qarr + qrow * 512 + h * 64 + 32 + quad * 8);
    {   // inline oq: logical k 64..95 -> oq[0..15] then zeros; 0.25*log2e folded
        uint4 a2u = {0u, 0u, 0u, 0u};
        if (quad < 2) {
            float o0 = obs[qrow * 2], o1 = obs[qrow * 2 + 1];
            int f = h * 16 + quad * 8;
            const float sc = 0.25f * L2E;
            __bf16 tmp[8];
            #pragma unroll
            for (int j = 0; j < 8; j++)
                tmp[j] = (__bf16)(sc * (o0 * Woq[f + j] + o1 * Woq[128 + f + j]
                                        + boq[f + j]));
            a2u = *(uint4*)tmp;
        }
        bq_[2] = *(bf16x8*)&a2u;
    }

    // var-bias: row (n&31) fixed per lane; m&31 = (ct&1)*16 + quad*4 + r
    const int rm = (w & 1) * 16 + l16;
    float4 vbA = *(const float4*)(varb + h * 1024 + rm * 32 + quad * 4);
    float4 vbB = *(const float4*)(varb + h * 1024 + rm * 32 + 16 + quad * 4);
    float vA[4] = {vbA.x * L2E, vbA.y * L2E, vbA.z * L2E, vbA.w * L2E};
    float vB[4] = {vbB.x * L2E, vbB.y * L2E, vbB.z * L2E, vbB.w * L2E};
    const int tn = 2 * qt + (w >> 1);

    // staging maps — identical to R9
    const int ck = (tid & 15) ^ ((tid >> 4) & 7);
    const __bf16* kbase = kx + (size_t)bh * NN * 96 + ck * 8;
    const int cv = (tid & 7) ^ ((tid >> 3) & 7);
    const __bf16* vbase = vt + (size_t)bh * 64 * 1536 + cv * 8;

    // Ps chunk-XOR offsets (bytes), precomputed once
    int wo2[4], ro2[2];
    #pragma unroll
    for (int ct = 0; ct < 4; ct++)
        wo2[ct] = (((ct * 2 + (quad >> 1)) ^ (nl & 7)) * 16) + (quad & 1) * 8;
    #pragma unroll
    for (int ks = 0; ks < 2; ks++)
        ro2[ks] = ((ks * 4 + quad) ^ (nl & 7)) * 16;
    char* psrow = (char*)Ps + nl * 128;

    f32x4 zero4 = {0.f, 0.f, 0.f, 0.f};
    f32x4 o[4];
    float lp = 0.f;
    #pragma unroll
    for (int i = 0; i < 4; i++) o[i] = zero4;

    char* ldsK = (char*)Ks;
    char* ldsV = (char*)Vs;

    for (int mt = 0; mt < 24; mt++) {
        const int m0 = mt * 64;
        __syncthreads();
        #pragma unroll
        for (int i = 0; i < 4; i++) {
            int row = i * 16 + (tid >> 4);
            GLOAD_LDS(kbase + (size_t)(m0 + row) * 96, ldsK + i * 4096 + tid * 16);
        }
        #pragma unroll
        for (int i = 0; i < 2; i++) {
            int row = i * 32 + (tid >> 3);
            GLOAD_LDS(vbase + (size_t)row * 1536 + m0, ldsV + i * 4096 + tid * 16);
        }
        __syncthreads();

        // ---- S^T = K.Q^T over K=96 (A = K fragment, B = Q fragment) ----
        f32x4 sc[4];
        #pragma unroll
        for (int ct = 0; ct < 4; ct++) {
            f32x4 d = zero4;
            int row = ct * 16 + l16;
            #pragma unroll
            for (int ks = 0; ks < 3; ks++) {
                bf16x8 kf = *(const bf16x8*)((const char*)Ks + row * 256
                                + (((ks * 4 + quad) ^ (row & 7)) * 16));
                d = __builtin_amdgcn_mfma_f32_16x16x32_bf16(kf, bq_[ks], d, 0, 0, 0);
            }
            sc[ct] = d;
        }
        // ---- biases + exp2; packed b64 P-stores ----
        float tb0 = rts[tn - 2 * mt + 47];
        float tb1 = rts[tn - 2 * mt + 46];
        #pragma unroll
        for (int ct = 0; ct < 4; ct++) {
            float tb = (ct & 2) ? tb1 : tb0;
            const float* vv = (ct & 1) ? vB : vA;
            __bf16 pk[4];
            #pragma unroll
            for (int r = 0; r < 4; r++) {
                float p = exp2f(sc[ct][r] + tb + vv[r]);
                lp += p;
                pk[r] = (__bf16)p;
            }
            *(uint2*)(psrow + wo2[ct]) = *(uint2*)pk;
        }
        // ---- O^T += V^T.P^T (A = V fragment, B = P^T fragment) ----
        #pragma unroll
        for (int ks = 0; ks < 2; ks++) {
            bf16x8 pf = *(const bf16x8*)(psrow + ro2[ks]);
            #pragma unroll
            for (int dt = 0; dt < 4; dt++) {
                int rw = dt * 16 + l16;
                bf16x8 vf = *(const bf16x8*)((const char*)Vs + rw * 128
                                + (((ks * 4 + quad) ^ (rw & 7)) * 16));
                o[dt] = __builtin_amdgcn_mfma_f32_16x16x32_bf16(vf, pf, o[dt], 0, 0, 0);
            }
        }
    }

    // final l reduction (across quads only) + packed epilogue
    lp += __shfl_xor(lp, 16);
    lp += __shfl_xor(lp, 32);
    float inv = 1.0f / lp;
    size_t abase = ((size_t)b * NN + n0 + nl) * 512 + h * 64 + quad * 4;
    #pragma unroll
    for (int dt = 0; dt < 4; dt++) {
        __bf16 ov[4];
        #pragma unroll
        for (int r = 0; r < 4; r++) ov[r] = (__bf16)(o[dt][r] * inv);
        *(uint2*)(aout + abase + dt * 16) = *(uint2*)ov;
    }
}

extern "C" void kernel_launch(void* const* d_in, const int* in_sizes, int n_in,
                              void* d_out, int out_size, void* d_ws, size_t ws_size,
                              hipStream_t stream)
{
    const float* h_   = (const float*)d_in[0];
    const float* obs  = (const float*)d_in[1];
    const float* Wq   = (const float*)d_in[2];
    const float* bq   = (const float*)d_in[3];
    const float* Wk   = (const float*)d_in[4];
    const float* bk   = (const float*)d_in[5];
    const float* Wv   = (const float*)d_in[6];
    const float* bv   = (const float*)d_in[7];
    const float* Wo   = (const float*)d_in[8];
    const float* bo   = (const float*)d_in[9];
    const float* Woq  = (const float*)d_in[10];
    const float* boq  = (const float*)d_in[11];
    const float* Wok  = (const float*)d_in[12];
    const float* bok  = (const float*)d_in[13];
    const float* varb = (const float*)d_in[14];
    const float* rtb  = (const float*)d_in[15];
    float* out = (float*)d_out;

    char* ws = (char*)d_ws;
    __bf16* h_bf    = (__bf16*)ws;                 ws += (size_t)NBN * 512 * 2;   // aliased by vt
    __bf16* qarr    = (__bf16*)ws;                 ws += (size_t)NBN * 512 * 2;
    __bf16* varr    = (__bf16*)ws;                 ws += (size_t)NBN * 512 * 2;
    __bf16* kx      = (__bf16*)ws;                 ws += ((size_t)32 * NN * 96 + 64) * 2;
    __bf16* attnout = (__bf16*)ws;                 ws += (size_t)NBN * 512 * 2;
    __bf16* WcatT   = (__bf16*)ws;                 ws += (size_t)1536 * 512 * 2;
    __bf16* WoT     = (__bf16*)ws;                 ws += (size_t)512 * 512 * 2;
    float*  biascat = (float*)ws;                  ws += 1536 * 4;
    __bf16* vt      = h_bf;   // h_bf dead after QKV GEMM; kvprep runs after it

    prep<<<dim3(2176), dim3(256), 0, stream>>>(
        h_, obs, Wq, Wk, Wv, Wo, bq, bk, bv, Wok, bok,
        h_bf, WcatT, WoT, biascat, kx);
    gemm_mfma<128, true><<<dim3(12, 48), dim3(256), 0, stream>>>(
        h_bf, WcatT, biascat, nullptr, qarr, kx, varr);
    kvprep<<<dim3(24, 32), dim3(256), 0, stream>>>(varr, vt);
    attn_mfma<<<dim3(24, 32), dim3(256), 0, stream>>>(qarr, kx, vt, obs, Woq, boq,
                                                      varb, rtb, attnout);
    gemm_mfma<64, false><<<dim3(4, 96), dim3(256), 0, stream>>>(
        attnout, WoT, bo, out, nullptr, nullptr, nullptr);
}

// Round 11
// 179.717 us; speedup vs baseline: 1.0495x; 1.0495x over previous
//
#include <hip/hip_runtime.h>
#include <math.h>

typedef __bf16 bf16x8 __attribute__((ext_vector_type(8)));
typedef float f32x4 __attribute__((ext_vector_type(4)));

#define NB 4
#define NT 48
#define NV 32
#define ND 512
#define NH 8
#define NN 1536   // T*V
#define NBN 6144  // B*N
#define L2E 1.44269504f

#define GLOAD_LDS(g, l) \
    __builtin_amdgcn_global_load_lds( \
        (const __attribute__((address_space(1))) void*)(g), \
        (__attribute__((address_space(3))) void*)(l), 16, 0, 0)

// ---------------------------------------------------------------------------
// prep: fused conv_h (blocks 0..1535) + weight transpose (1536..1791) +
// kx obs/zero segments (1792..2175).  log2e folded into Wq/bq scale.
// ---------------------------------------------------------------------------
__global__ __launch_bounds__(256) void prep(
    const float* __restrict__ h, const float* __restrict__ obs,
    const float* __restrict__ Wq, const float* __restrict__ Wk,
    const float* __restrict__ Wv, const float* __restrict__ Wo,
    const float* __restrict__ bq, const float* __restrict__ bk,
    const float* __restrict__ bv,
    const float* __restrict__ Wok, const float* __restrict__ bok,
    __bf16* __restrict__ h_bf, __bf16* __restrict__ WcatT,
    __bf16* __restrict__ WoT, float* __restrict__ biascat,
    __bf16* __restrict__ kx)
{
    __shared__ float ts[64][68];
    const int tid = threadIdx.x;
    const int bx = blockIdx.x;
    if (bx < 1536) {
        int t = bx * 256 + tid;
        const float4* src = (const float4*)h + (size_t)t * 2;
        float4 a = src[0], b = src[1];
        __bf16 r[8] = {(__bf16)a.x, (__bf16)a.y, (__bf16)a.z, (__bf16)a.w,
                       (__bf16)b.x, (__bf16)b.y, (__bf16)b.z, (__bf16)b.w};
        *(uint4*)(h_bf + (size_t)t * 8) = *(uint4*)r;
    } else if (bx < 1792) {
        int bw = bx - 1536;
        const int p = bw >> 6, tile = bw & 63;
        const int k0 = (tile >> 3) * 64, c0 = (tile & 7) * 64;
        const float* W = (p == 0) ? Wq : (p == 1) ? Wk : (p == 2) ? Wv : Wo;
        const float scale = (p == 0) ? 0.125f * L2E : 1.0f;
        #pragma unroll
        for (int i = 0; i < 4; i++) {
            int r = (tid >> 4) + i * 16;
            float4 v = *(const float4*)(W + (size_t)(k0 + r) * 512 + c0 + (tid & 15) * 4);
            *(float4*)&ts[r][(tid & 15) * 4] = v;
        }
        __syncthreads();
        __bf16 tmp[16];
        #pragma unroll
        for (int j = 0; j < 16; j++)
            tmp[j] = (__bf16)(ts[(tid & 3) * 16 + j][tid >> 2] * scale);
        int crow = c0 + (tid >> 2);
        __bf16* dst = (p < 3)
            ? WcatT + ((size_t)(p * 512 + crow)) * 512 + k0 + (tid & 3) * 16
            : WoT   + ((size_t)crow) * 512 + k0 + (tid & 3) * 16;
        *(uint4*)dst = *(uint4*)tmp;
        *(uint4*)(dst + 8) = *(uint4*)(tmp + 8);
        if (p < 3 && k0 == 0 && tid < 64) {
            const float* bb = (p == 0) ? bq : (p == 1) ? bk : bv;
            biascat[p * 512 + c0 + tid] = bb[c0 + tid] * scale;
        }
    } else {
        int t = (bx - 1792) * 256 + tid;               // 0..98303
        int row = t >> 1, half = t & 1;                // row = bh*1536 + n
        __bf16* dst = kx + (size_t)row * 96 + 64 + half * 16;
        if (half == 0) {
            int bh = row / NN, n = row - bh * NN;
            int b = bh >> 3, hh = bh & 7;
            size_t bn = (size_t)b * NN + n;
            float o0 = obs[bn * 2], o1 = obs[bn * 2 + 1];
            int f = hh * 16;
            __bf16 tmp[16];
            #pragma unroll
            for (int j = 0; j < 16; j++)
                tmp[j] = (__bf16)(o0 * Wok[f + j] + o1 * Wok[128 + f + j] + bok[f + j]);
            *(uint4*)dst       = *(uint4*)tmp;
            *(uint4*)(dst + 8) = *(uint4*)(tmp + 8);
        } else {
            uint4 z = {0, 0, 0, 0};
            *(uint4*)dst       = z;
            *(uint4*)(dst + 8) = z;
        }
    }
}

// ---------------------------------------------------------------------------
// bf16 MFMA GEMM (global_load_lds staging + XOR-swizzled LDS).
// LDS-staged epilogue: acc -> Cs tile -> coalesced b128 global stores.
// BF16OUT (QKV): n0<512 -> qarr row-major; 512<=n0<1024 -> kx (head rows);
//                n0>=1024 -> vt DIRECTLY (transposed via LDS) — kvprep fused.
// else: fp32 out [M][512].
// ---------------------------------------------------------------------------
template<int TM, bool BF16OUT>
__global__ __launch_bounds__(256) void gemm_mfma(
    const __bf16* __restrict__ A, const __bf16* __restrict__ Bt,
    const float* __restrict__ bias, float* __restrict__ Cf,
    __bf16* __restrict__ qarr, __bf16* __restrict__ kx,
    __bf16* __restrict__ vt)
{
    constexpr int MT = TM / 32;
    __shared__ __align__(16) char smem[34816];
    __bf16 (*As)[32] = (__bf16(*)[32])smem;
    __bf16 (*Bs)[32] = (__bf16(*)[32])(smem + TM * 64);
    const int tid = threadIdx.x;
    const int w = tid >> 6, lane = tid & 63;
    const int quad = lane >> 4, l16 = lane & 15;
    const int wm = w >> 1, wn = w & 1;
    const int n0 = blockIdx.x * 128, m0 = blockIdx.y * TM;

    const int sm = tid >> 2;
    const int sk = ((tid & 3) ^ ((sm >> 1) & 3)) * 8;
    const __bf16* aptr = A  + (size_t)(m0 + sm) * 512 + sk;
    const __bf16* bptr = Bt + (size_t)(n0 + sm) * 512 + sk;
    __bf16* lA = (__bf16*)As + tid * 8;
    __bf16* lB = (__bf16*)Bs + tid * 8;

    f32x4 zero4 = {0.f, 0.f, 0.f, 0.f};
    f32x4 acc[MT][4];
    #pragma unroll
    for (int i = 0; i < MT; i++)
        #pragma unroll
        for (int j = 0; j < 4; j++) acc[i][j] = zero4;

    for (int kt = 0; kt < 512; kt += 32) {
        __syncthreads();
        GLOAD_LDS(aptr + kt, lA);
        if (TM == 128) GLOAD_LDS(aptr + 64 * 512 + kt, lA + 2048);
        GLOAD_LDS(bptr + kt, lB);
        GLOAD_LDS(bptr + 64 * 512 + kt, lB + 2048);
        __syncthreads();
        bf16x8 af[MT], bfr[4];
        #pragma unroll
        for (int mt = 0; mt < MT; mt++) {
            int rr = wm * (TM / 2) + mt * 16 + l16;
            af[mt] = *(const bf16x8*)&As[rr][(quad ^ ((rr >> 1) & 3)) * 8];
        }
        #pragma unroll
        for (int nt = 0; nt < 4; nt++) {
            int rr = wn * 64 + nt * 16 + l16;
            bfr[nt] = *(const bf16x8*)&Bs[rr][(quad ^ ((rr >> 1) & 3)) * 8];
        }
        #pragma unroll
        for (int mt = 0; mt < MT; mt++)
            #pragma unroll
            for (int nt = 0; nt < 4; nt++)
                acc[mt][nt] = __builtin_amdgcn_mfma_f32_16x16x32_bf16(
                    af[mt], bfr[nt], acc[mt][nt], 0, 0, 0);
    }

    __syncthreads();   // frag reads done; smem becomes C-stage
    if (BF16OUT) {
        if (n0 >= 1024) {
            // ---- V tile: stage TRANSPOSED (CsT[col][136 rows]), write vt ----
            __bf16* CsT = (__bf16*)smem;
            #pragma unroll
            for (int nt = 0; nt < 4; nt++) {
                int cl = wn * 64 + nt * 16 + l16;
                float bia = bias[n0 + cl];
                #pragma unroll
                for (int mt = 0; mt < MT; mt++) {
                    int rl0 = wm * (TM / 2) + mt * 16 + quad * 4;
                    __bf16 pk[4];
                    #pragma unroll
                    for (int r = 0; r < 4; r++)
                        pk[r] = (__bf16)(acc[mt][nt][r] + bia);
                    *(uint2*)&CsT[cl * 136 + rl0] = *(uint2*)pk;
                }
            }
            __syncthreads();
            int cl = tid >> 1, half = tid & 1;
            int f0 = (n0 + cl) & 511;
            int hh = f0 >> 6, d = f0 & 63;
            int bidx = m0 / NN, nm = m0 - bidx * NN;
            __bf16* dst = vt + ((size_t)(bidx * 8 + hh) * 64 + d) * 1536
                             + nm + half * 64;
            #pragma unroll
            for (int j = 0; j < 8; j++) {
                uint4 v = *(uint4*)&CsT[cl * 136 + half * 64 + j * 8];
                *(uint4*)(dst + j * 8) = v;
            }
        } else {
            // ---- Q/K tile: row-major stage, routed stores ----
            __bf16* Cs = (__bf16*)smem;               // [TM][132]
            #pragma unroll
            for (int mt = 0; mt < MT; mt++)
                #pragma unroll
                for (int nt = 0; nt < 4; nt++) {
                    int cl = wn * 64 + nt * 16 + l16;
                    float bia = bias[n0 + cl];
                    #pragma unroll
                    for (int r = 0; r < 4; r++) {
                        int rl = wm * (TM / 2) + mt * 16 + quad * 4 + r;
                        Cs[rl * 132 + cl] = (__bf16)(acc[mt][nt][r] + bia);
                    }
                }
            __syncthreads();
            int rl = tid >> 1, hb = tid & 1;
            int grow = m0 + rl;
            int col0 = n0 + hb * 64;
            int p = col0 >> 9, f0 = col0 & 511, hh = f0 >> 6;
            int bidx = grow / NN, n = grow - bidx * NN;
            __bf16* dst = (p == 0) ? qarr + (size_t)grow * 512 + f0
                                   : kx + ((size_t)(bidx * 8 + hh) * NN + n) * 96;
            #pragma unroll
            for (int j = 0; j < 8; j++) {
                uint2 lo = *(uint2*)&Cs[rl * 132 + hb * 64 + j * 8];
                uint2 hi = *(uint2*)&Cs[rl * 132 + hb * 64 + j * 8 + 4];
                uint4 v = {lo.x, lo.y, hi.x, hi.y};
                *(uint4*)(dst + j * 8) = v;
            }
        }
    } else {
        float* Csf = (float*)smem;                // [64][132]
        #pragma unroll
        for (int mt = 0; mt < MT; mt++)
            #pragma unroll
            for (int nt = 0; nt < 4; nt++) {
                int cl = wn * 64 + nt * 16 + l16;
                float bia = bias[n0 + cl];
                #pragma unroll
                for (int r = 0; r < 4; r++) {
                    int rl = wm * (TM / 2) + mt * 16 + quad * 4 + r;
                    Csf[rl * 132 + cl] = acc[mt][nt][r] + bia;
                }
            }
        __syncthreads();
        int rl = tid >> 2, q4 = tid & 3;
        float* dst = Cf + (size_t)(m0 + rl) * 512 + n0 + q4 * 32;
        #pragma unroll
        for (int j = 0; j < 8; j++) {
            uint4 v = *(uint4*)&Csf[rl * 132 + q4 * 32 + j * 4];
            *(uint4*)(dst + j * 4) = v;
        }
    }
}

// ---------------------------------------------------------------------------
// Flash attention, transposed orientation (S^T = K.Q^T, O^T = V^T.P^T).
// Grid (32 bh, 24 qt): XCD = bh%8 -> each XCD's L2 holds 4 bh's K/V (~1.9 MB)
// so the 24 same-bh blocks hit L2, not HBM. Staging identical to R10.
// LDS ~32.4 KB.
// ---------------------------------------------------------------------------
__global__ __launch_bounds__(256) void attn_mfma(
    const __bf16* __restrict__ qarr, const __bf16* __restrict__ kx,
    const __bf16* __restrict__ vt, const float* __restrict__ obs,
    const float* __restrict__ Woq, const float* __restrict__ boq,
    const float* __restrict__ varb, const float* __restrict__ rtb,
    __bf16* __restrict__ aout)
{
    __shared__ __align__(16) __bf16 Ks[64][128];  // [m][128]: 8 content,4 obs,4 junk
    __shared__ __align__(16) __bf16 Vs[64][64];   // [d][m] swizzled
    __shared__ __align__(16) __bf16 Ps[64][64];   // [n][m] chunk-XOR swizzled
    __shared__ float rts[96];

    const int tid = threadIdx.x;
    const int w = tid >> 6, lane = tid & 63;
    const int quad = lane >> 4, l16 = lane & 15;
    const int bh = blockIdx.x, qt = blockIdx.y;   // XCD-locality swizzle
    const int b = bh >> 3, h = bh & 7;
    const int n0 = qt * 64;

    if (tid < 95) rts[tid] = rtb[h * 95 + tid] * L2E;

    // Q fragments (B-operand): lane l16 holds row n = w*16+l16
    const int nl = w * 16 + l16;
    const size_t qrow = (size_t)(b * NN + n0 + nl);
    bf16x8 bq_[3];
    bq_[0] = *(const bf16x8*)(qarr + qrow * 512 + h * 64 + quad * 8);
    bq_[1] = *(const bf16x8*)(qarr + qrow * 512 + h * 64 + 32 + quad * 8);
    {   // inline oq: logical k 64..95 -> oq[0..15] then zeros; 0.25*log2e folded
        uint4 a2u = {0u, 0u, 0u, 0u};
        if (quad < 2) {
            float o0 = obs[qrow * 2], o1 = obs[qrow * 2 + 1];
            int f = h * 16 + quad * 8;
            const float sc = 0.25f * L2E;
            __bf16 tmp[8];
            #pragma unroll
            for (int j = 0; j < 8; j++)
                tmp[j] = (__bf16)(sc * (o0 * Woq[f + j] + o1 * Woq[128 + f + j]
                                        + boq[f + j]));
            a2u = *(uint4*)tmp;
        }
        bq_[2] = *(bf16x8*)&a2u;
    }

    // var-bias: row (n&31) fixed per lane; m&31 = (ct&1)*16 + quad*4 + r
    const int rm = (w & 1) * 16 + l16;
    float4 vbA = *(const float4*)(varb + h * 1024 + rm * 32 + quad * 4);
    float4 vbB = *(const float4*)(varb + h * 1024 + rm * 32 + 16 + quad * 4);
    float vA[4] = {vbA.x * L2E, vbA.y * L2E, vbA.z * L2E, vbA.w * L2E};
    float vB[4] = {vbB.x * L2E, vbB.y * L2E, vbB.z * L2E, vbB.w * L2E};
    const int tn = 2 * qt + (w >> 1);

    // staging maps — identical to R10
    const int ck = (tid & 15) ^ ((tid >> 4) & 7);
    const __bf16* kbase = kx + (size_t)bh * NN * 96 + ck * 8;
    const int cv = (tid & 7) ^ ((tid >> 3) & 7);
    const __bf16* vbase = vt + (size_t)bh * 64 * 1536 + cv * 8;

    // Ps chunk-XOR offsets (bytes), precomputed once
    int wo2[4], ro2[2];
    #pragma unroll
    for (int ct = 0; ct < 4; ct++)
        wo2[ct] = (((ct * 2 + (quad >> 1)) ^ (nl & 7)) * 16) + (quad & 1) * 8;
    #pragma unroll
    for (int ks = 0; ks < 2; ks++)
        ro2[ks] = ((ks * 4 + quad) ^ (nl & 7)) * 16;
    char* psrow = (char*)Ps + nl * 128;

    f32x4 zero4 = {0.f, 0.f, 0.f, 0.f};
    f32x4 o[4];
    float lp = 0.f;
    #pragma unroll
    for (int i = 0; i < 4; i++) o[i] = zero4;

    char* ldsK = (char*)Ks;
    char* ldsV = (char*)Vs;

    for (int mt = 0; mt < 24; mt++) {
        const int m0 = mt * 64;
        __syncthreads();
        #pragma unroll
        for (int i = 0; i < 4; i++) {
            int row = i * 16 + (tid >> 4);
            GLOAD_LDS(kbase + (size_t)(m0 + row) * 96, ldsK + i * 4096 + tid * 16);
        }
        #pragma unroll
        for (int i = 0; i < 2; i++) {
            int row = i * 32 + (tid >> 3);
            GLOAD_LDS(vbase + (size_t)row * 1536 + m0, ldsV + i * 4096 + tid * 16);
        }
        __syncthreads();

        // ---- S^T = K.Q^T over K=96 ----
        f32x4 sc[4];
        #pragma unroll
        for (int ct = 0; ct < 4; ct++) {
            f32x4 d = zero4;
            int row = ct * 16 + l16;
            #pragma unroll
            for (int ks = 0; ks < 3; ks++) {
                bf16x8 kf = *(const bf16x8*)((const char*)Ks + row * 256
                                + (((ks * 4 + quad) ^ (row & 7)) * 16));
                d = __builtin_amdgcn_mfma_f32_16x16x32_bf16(kf, bq_[ks], d, 0, 0, 0);
            }
            sc[ct] = d;
        }
        // ---- biases + exp2; packed b64 P-stores ----
        float tb0 = rts[tn - 2 * mt + 47];
        float tb1 = rts[tn - 2 * mt + 46];
        #pragma unroll
        for (int ct = 0; ct < 4; ct++) {
            float tb = (ct & 2) ? tb1 : tb0;
            const float* vv = (ct & 1) ? vB : vA;
            __bf16 pk[4];
            #pragma unroll
            for (int r = 0; r < 4; r++) {
                float p = exp2f(sc[ct][r] + tb + vv[r]);
                lp += p;
                pk[r] = (__bf16)p;
            }
            *(uint2*)(psrow + wo2[ct]) = *(uint2*)pk;
        }
        // ---- O^T += V^T.P^T ----
        #pragma unroll
        for (int ks = 0; ks < 2; ks++) {
            bf16x8 pf = *(const bf16x8*)(psrow + ro2[ks]);
            #pragma unroll
            for (int dt = 0; dt < 4; dt++) {
                int rw = dt * 16 + l16;
                bf16x8 vf = *(const bf16x8*)((const char*)Vs + rw * 128
                                + (((ks * 4 + quad) ^ (rw & 7)) * 16));
                o[dt] = __builtin_amdgcn_mfma_f32_16x16x32_bf16(vf, pf, o[dt], 0, 0, 0);
            }
        }
    }

    // final l reduction (across quads only) + packed epilogue
    lp += __shfl_xor(lp, 16);
    lp += __shfl_xor(lp, 32);
    float inv = 1.0f / lp;
    size_t abase = ((size_t)b * NN + n0 + nl) * 512 + h * 64 + quad * 4;
    #pragma unroll
    for (int dt = 0; dt < 4; dt++) {
        __bf16 ov[4];
        #pragma unroll
        for (int r = 0; r < 4; r++) ov[r] = (__bf16)(o[dt][r] * inv);
        *(uint2*)(aout + abase + dt * 16) = *(uint2*)ov;
    }
}

extern "C" void kernel_launch(void* const* d_in, const int* in_sizes, int n_in,
                              void* d_out, int out_size, void* d_ws, size_t ws_size,
                              hipStream_t stream)
{
    const float* h_   = (const float*)d_in[0];
    const float* obs  = (const float*)d_in[1];
    const float* Wq   = (const float*)d_in[2];
    const float* bq   = (const float*)d_in[3];
    const float* Wk   = (const float*)d_in[4];
    const float* bk   = (const float*)d_in[5];
    const float* Wv   = (const float*)d_in[6];
    const float* bv   = (const float*)d_in[7];
    const float* Wo   = (const float*)d_in[8];
    const float* bo   = (const float*)d_in[9];
    const float* Woq  = (const float*)d_in[10];
    const float* boq  = (const float*)d_in[11];
    const float* Wok  = (const float*)d_in[12];
    const float* bok  = (const float*)d_in[13];
    const float* varb = (const float*)d_in[14];
    const float* rtb  = (const float*)d_in[15];
    float* out = (float*)d_out;

    char* ws = (char*)d_ws;
    __bf16* h_bf    = (__bf16*)ws;                 ws += (size_t)NBN * 512 * 2;
    __bf16* qarr    = (__bf16*)ws;                 ws += (size_t)NBN * 512 * 2;
    __bf16* vt      = (__bf16*)ws;                 ws += (size_t)NBN * 512 * 2;
    __bf16* kx      = (__bf16*)ws;                 ws += ((size_t)32 * NN * 96 + 64) * 2;
    __bf16* attnout = (__bf16*)ws;                 ws += (size_t)NBN * 512 * 2;
    __bf16* WcatT   = (__bf16*)ws;                 ws += (size_t)1536 * 512 * 2;
    __bf16* WoT     = (__bf16*)ws;                 ws += (size_t)512 * 512 * 2;
    float*  biascat = (float*)ws;                  ws += 1536 * 4;

    prep<<<dim3(2176), dim3(256), 0, stream>>>(
        h_, obs, Wq, Wk, Wv, Wo, bq, bk, bv, Wok, bok,
        h_bf, WcatT, WoT, biascat, kx);
    gemm_mfma<128, true><<<dim3(12, 48), dim3(256), 0, stream>>>(
        h_bf, WcatT, biascat, nullptr, qarr, kx, vt);
    attn_mfma<<<dim3(32, 24), dim3(256), 0, stream>>>(qarr, kx, vt, obs, Woq, boq,
                                                      varb, rtb, attnout);
    gemm_mfma<64, false><<<dim3(4, 96), dim3(256), 0, stream>>>(
        attnout, WoT, bo, out, nullptr, nullptr, nullptr);
}